// Round 9
// baseline (28.790 us; speedup 1.0000x reference)
//
#include <hip/hip_runtime.h>

// Problem shape (fixed by the reference setup)
#define TT 512
#define BB 32
#define FF 256
#define LL 8
#define NCHAIN (BB * FF * LL)   // 65536 chains
#define NGROUP (NCHAIN / 4)     // 16384 float4 groups (4 consecutive l's)
#define NCHUNK 32
#define TC (TT / NCHUNK)        // 16 steps per chunk

typedef float f32x4 __attribute__((ext_vector_type(4)));

// Single-pass lookback kernel (round-8 structure, 28.4 us). Round-9 change:
// REGULAR stores instead of nontemporal (single-variable A/B) — fillBuffer
// reaches ~7 TB/s with regular stores; NT may cost TCC write-combining.
//
// Block unit: (chunk, b, half-of-f).
//   chunk = blockIdx>>6 (block-uniform); blockLocal = blockIdx&63;
//   b = blockLocal>>1 (block-uniform -> resets scalar-broadcast, and all
//   reset-dependent control flow is wave-uniform);
//   idx = ((blockLocal&1)<<8)|tid; f = idx>>1; h = idx&1; g = (b<<9)|idx.
// Entering state: scan resets backward from t0-1 for the most recent reset
// (expected ~2 steps at p=0.5). State after a reset step t_r is exactly
// x[t_r], so replay the reset-free gap (t_r, t0) and go. If no reset ever
// occurred (never for this data, but handled exactly): replay from carry.
__global__ __launch_bounds__(256) void trace_rnn_lookback(
    const float* __restrict__ features,  // [T,B,F]
    const int*   __restrict__ resets,    // [T,B]
    const float* __restrict__ carry,     // [B,F,L]
    const float* __restrict__ lambdas,   // [L]
    f32x4*       __restrict__ out4)      // [NGROUP] final, then [T][NGROUP] ys
{
    const int chunk      = blockIdx.x >> 6;
    const int blockLocal = blockIdx.x & 63;
    const int b   = blockLocal >> 1;
    const int idx = ((blockLocal & 1) << 8) | threadIdx.x;
    const int f   = idx >> 1;
    const int h   = idx & 1;
    const int g   = (b << 9) | idx;

    const f32x4 lam  = ((const f32x4*)lambdas)[h];
    const f32x4 onem = 1.0f - lam;
    const int   t0   = chunk * TC;

    // ---- Entering state for this chunk (state after step t0-1) ----
    f32x4 s;
    if (chunk == 0) {
        s = ((const f32x4*)carry)[g];
    } else {
        int tr = t0 - 1;                      // wave-uniform backward scan
        while (tr >= 0 && resets[(size_t)tr * BB + b] == 0) --tr;
        int tstart;
        if (tr < 0) {
            s = ((const f32x4*)carry)[g];     // no reset in prefix: from carry
            tstart = 0;
        } else {
            const float xr = features[(size_t)tr * (BB * FF) + b * FF + f];
            s = xr;                           // state after reset step == x
            tstart = tr + 1;
        }
        // Replay (reset-free by construction) gap [tstart, t0).
        for (int t = tstart; t < t0; ++t) {
            const float x = features[(size_t)t * (BB * FF) + b * FF + f];
            #pragma unroll
            for (int j = 0; j < 4; ++j)
                s[j] = fmaf(lam[j], s[j], onem[j] * x);
        }
    }

    // ---- Main chunk: scan + write every step ----
    const float* fptr = features + (size_t)t0 * (BB * FF) + b * FF + f;
    const int*   rptr = resets + (size_t)t0 * BB + b;
    f32x4*       yptr = out4 + NGROUP + (size_t)t0 * NGROUP + g;

    #pragma unroll
    for (int t = 0; t < TC; ++t) {
        const float x = fptr[(size_t)t * (BB * FF)];
        const int   r = rptr[(size_t)t * BB];
        #pragma unroll
        for (int j = 0; j < 4; ++j) {
            const float v = fmaf(lam[j], s[j], onem[j] * x);
            s[j] = r ? x : v;
        }
        yptr[(size_t)t * NGROUP] = s;   // regular store (was nontemporal)
    }

    // final_trace (FIRST output in the concatenation)
    if (chunk == NCHUNK - 1) out4[g] = s;
}

extern "C" void kernel_launch(void* const* d_in, const int* in_sizes, int n_in,
                              void* d_out, int out_size, void* d_ws, size_t ws_size,
                              hipStream_t stream) {
    const float* features = (const float*)d_in[0];
    const int*   resets   = (const int*)d_in[1];
    const float* carry    = (const float*)d_in[2];
    const float* lambdas  = (const float*)d_in[3];
    f32x4* out4 = (f32x4*)d_out;

    const int grid = NCHUNK * 64;  // 2048 blocks, 8/CU, 32 waves/CU
    trace_rnn_lookback<<<grid, 256, 0, stream>>>(
        features, resets, carry, lambdas, out4);
}